// Round 2
// baseline (392.271 us; speedup 1.0000x reference)
//
#include <hip/hip_runtime.h>

#define N_NODE   4096
#define PLANE    (N_NODE * N_NODE)   // 16777216 floats per Chebyshev plane
#define TAU_MAX  10.0f
#define INV_SCALE 0.01f              // 1/(T1-T0)

typedef float f32x4 __attribute__((ext_vector_type(4)));
typedef float f32x2 __attribute__((ext_vector_type(2)));

// Stable Softplus(beta=100): log(1+exp(100 z))/100 = (max(100z,0)+log1p(exp(-|100z|)))/100
__device__ __forceinline__ float sp100(float z) {
    float a = 100.0f * z;
    float e = __expf(-fabsf(a));
    return (fmaxf(a, 0.0f) + __logf(1.0f + e)) * 0.01f;
}

// One basis-n MLP: 1 -> 5 -> 5 -> 1, softplus100 activations on the two hidden layers.
// All weight indices are wave-uniform -> scalar loads (s_load) + SGPR operands in v_fma.
__device__ __forceinline__ float mlp_n(float t,
                                       const float* __restrict__ W1,
                                       const float* __restrict__ b1,
                                       const float* __restrict__ W2,
                                       const float* __restrict__ b2,
                                       const float* __restrict__ W3,
                                       const float* __restrict__ b3,
                                       int n) {
    float h1[5];
#pragma unroll
    for (int w = 0; w < 5; ++w)
        h1[w] = sp100(fmaf(t, W1[n * 5 + w], b1[n * 5 + w]));

    float h2[5];
#pragma unroll
    for (int v = 0; v < 5; ++v) {
        float acc = b2[n * 5 + v];
#pragma unroll
        for (int w = 0; w < 5; ++w)
            acc = fmaf(h1[w], W2[n * 25 + w * 5 + v], acc);
        h2[v] = sp100(acc);
    }

    float o = b3[n];
#pragma unroll
    for (int w = 0; w < 5; ++w)
        o = fmaf(h2[w], W3[n * 5 + w], o);
    return o;
}

// Full per-sample evaluation given the 4 pre-gathered K_l values.
__device__ __forceinline__ float eval_sample(float dt, float ty_raw,
        const float* __restrict__ Wx1, const float* __restrict__ bx1,
        const float* __restrict__ Wx2, const float* __restrict__ bx2,
        const float* __restrict__ Wx3, const float* __restrict__ bx3,
        const float* __restrict__ Wy1, const float* __restrict__ by1,
        const float* __restrict__ Wy2, const float* __restrict__ by2,
        const float* __restrict__ Wy3, const float* __restrict__ by3,
        const float* __restrict__ W,
        float kl0, float kl1, float kl2, float kl3) {
    float tx = dt * INV_SCALE;
    float ty = ty_raw * INV_SCALE;   // (t_y - T0)/scale, T0 = 0

    float s0 = 0.f, s1 = 0.f, s2 = 0.f, s3 = 0.f;
#pragma unroll
    for (int n = 0; n < 4; ++n) {
        float xb = mlp_n(tx, Wx1, bx1, Wx2, bx2, Wx3, bx3, n);
        float yb = mlp_n(ty, Wy1, by1, Wy2, by2, Wy3, by3, n);
        float k = xb * yb;
        s0 = fmaf(k, W[n * 4 + 0], s0);
        s1 = fmaf(k, W[n * 4 + 1], s1);
        s2 = fmaf(k, W[n * 4 + 2], s2);
        s3 = fmaf(k, W[n * 4 + 3], s3);
    }
    return fmaf(s0, kl0, fmaf(s1, kl1, fmaf(s2, kl2, s3 * kl3)));
}

// 2 samples per thread: float4 input loads, 8 gathers in flight before ~5400
// cycles of MLP issue, one residency generation (8192 waves), float2 stores.
__global__ __launch_bounds__(256)
void tdb_cheb_kernel(const float* __restrict__ x,   // [B,2] (t, node_idx)
                     const float* __restrict__ y,   // [B,2]
                     const float* __restrict__ Bm,  // [4, 4096, 4096]
                     const float* __restrict__ Wx1, const float* __restrict__ Wx2,
                     const float* __restrict__ Wx3,
                     const float* __restrict__ Wy1, const float* __restrict__ Wy2,
                     const float* __restrict__ Wy3,
                     const float* __restrict__ bx1, const float* __restrict__ bx2,
                     const float* __restrict__ bx3,
                     const float* __restrict__ by1, const float* __restrict__ by2,
                     const float* __restrict__ by3,
                     const float* __restrict__ W,   // [4,4]
                     float* __restrict__ out, int batch) {
    int p  = blockIdx.x * blockDim.x + threadIdx.x;
    int b0 = p << 1;
    if (b0 >= batch) return;
    bool paired = (b0 + 1) < batch;

    f32x4 xv, yv;
    if (paired) {
        // nontemporal: streamed once, keep L2 lines free for B gathers
        xv = __builtin_nontemporal_load(reinterpret_cast<const f32x4*>(x) + p);
        yv = __builtin_nontemporal_load(reinterpret_cast<const f32x4*>(y) + p);
    } else {
        const f32x2 xs = reinterpret_cast<const f32x2*>(x)[b0];
        const f32x2 ys = reinterpret_cast<const f32x2*>(y)[b0];
        xv = (f32x4){xs.x, xs.y, 0.f, 0.f};
        yv = (f32x4){ys.x, ys.y, 0.f, 0.f};
    }

    float dt0 = xv.x - yv.x;
    float dt1 = xv.z - yv.z;
    bool a0 = (dt0 <= TAU_MAX);
    bool a1 = paired && (dt1 <= TAU_MAX);

    // Issue all (up to 8) random gathers before any MLP compute; exec-masked
    // lanes fetch nothing. ~5400 VALU cycles below hide the miss latency.
    float k00 = 0.f, k01 = 0.f, k02 = 0.f, k03 = 0.f;
    float k10 = 0.f, k11 = 0.f, k12 = 0.f, k13 = 0.f;
    if (a0) {
        int idx = (int)yv.y * N_NODE + (int)xv.y;
        const float* q = Bm + idx;
        k00 = q[0];
        k01 = q[PLANE];
        k02 = q[2 * PLANE];
        k03 = q[3 * PLANE];
    }
    if (a1) {
        int idx = (int)yv.w * N_NODE + (int)xv.w;
        const float* q = Bm + idx;
        k10 = q[0];
        k11 = q[PLANE];
        k12 = q[2 * PLANE];
        k13 = q[3 * PLANE];
    }

    float r0 = 0.f, r1 = 0.f;
    if (a0) r0 = eval_sample(dt0, yv.x,
                             Wx1, bx1, Wx2, bx2, Wx3, bx3,
                             Wy1, by1, Wy2, by2, Wy3, by3,
                             W, k00, k01, k02, k03);
    if (a1) r1 = eval_sample(dt1, yv.z,
                             Wx1, bx1, Wx2, bx2, Wx3, bx3,
                             Wy1, by1, Wy2, by2, Wy3, by3,
                             W, k10, k11, k12, k13);

    if (paired) {
        f32x2 rv = {r0, r1};
        __builtin_nontemporal_store(rv, reinterpret_cast<f32x2*>(out) + p);
    } else {
        out[b0] = r0;
    }
}

extern "C" void kernel_launch(void* const* d_in, const int* in_sizes, int n_in,
                              void* d_out, int out_size, void* d_ws, size_t ws_size,
                              hipStream_t stream) {
    const float* x   = (const float*)d_in[0];
    const float* y   = (const float*)d_in[1];
    const float* Bm  = (const float*)d_in[2];
    const float* Wx1 = (const float*)d_in[3];
    const float* Wx2 = (const float*)d_in[4];
    const float* Wx3 = (const float*)d_in[5];
    const float* Wy1 = (const float*)d_in[6];
    const float* Wy2 = (const float*)d_in[7];
    const float* Wy3 = (const float*)d_in[8];
    const float* bx1 = (const float*)d_in[9];
    const float* bx2 = (const float*)d_in[10];
    const float* bx3 = (const float*)d_in[11];
    const float* by1 = (const float*)d_in[12];
    const float* by2 = (const float*)d_in[13];
    const float* by3 = (const float*)d_in[14];
    const float* W   = (const float*)d_in[15];
    float* out = (float*)d_out;

    int batch = in_sizes[0] / 2;            // x is [B,2]
    int nthreads = (batch + 1) >> 1;        // 2 samples per thread
    int block = 256;
    int grid  = (nthreads + block - 1) / block;
    tdb_cheb_kernel<<<grid, block, 0, stream>>>(x, y, Bm,
                                                Wx1, Wx2, Wx3, Wy1, Wy2, Wy3,
                                                bx1, bx2, bx3, by1, by2, by3,
                                                W, out, batch);
}